// Round 1
// baseline (89.076 us; speedup 1.0000x reference)
//
#include <hip/hip_runtime.h>
#include <hip/hip_bf16.h>

typedef float f32x4 __attribute__((ext_vector_type(4)));
typedef __bf16 bf16x8 __attribute__((ext_vector_type(8)));

#define NC 4096
#define ND 1024
#define EPSF 1e-10f

__device__ __forceinline__ unsigned short f2bf(float f) {
  unsigned int u = __float_as_uint(f);
  return (unsigned short)((u + 0x7fffu + ((u >> 16) & 1u)) >> 16);
}

// ---------------- zero workspace accumulators ----------------
__global__ void zero_kernel(float* p, int n) {
  int i = blockIdx.x * 256 + threadIdx.x;
  if (i < n) p[i] = 0.f;
}

// ---------------- scatter-count annotation targets ----------------
__global__ void count_kernel(const int* __restrict__ ann, float* counts, int n) {
  int t = blockIdx.x * 256 + threadIdx.x;
  if (t < n) {
    int idx = ann[t * 5 + 4];
    if (idx >= 0 && idx < NC) atomicAdd(&counts[idx], 1.0f);
  }
}

// ---------------- fp32 -> bf16 convert + row norms/sums ----------------
__global__ void convert_kernel(const float* __restrict__ F, const float* __restrict__ P,
                               unsigned short* __restrict__ Fb, unsigned short* __restrict__ Pb,
                               float* __restrict__ f2, float* __restrict__ p2,
                               float* __restrict__ psum) {
  int bid = blockIdx.x;
  bool isP = bid >= NC;
  int row = isP ? bid - NC : bid;
  const float* src = (isP ? P : F) + (size_t)row * ND;
  unsigned short* dst = (isP ? Pb : Fb) + (size_t)row * ND;
  int tid = threadIdx.x;
  float4 v = *reinterpret_cast<const float4*>(src + tid * 4);
  ushort4 o;
  o.x = f2bf(v.x); o.y = f2bf(v.y); o.z = f2bf(v.z); o.w = f2bf(v.w);
  *reinterpret_cast<ushort4*>(dst + tid * 4) = o;
  float sq = v.x * v.x + v.y * v.y + v.z * v.z + v.w * v.w;
  float sm = v.x + v.y + v.z + v.w;
  #pragma unroll
  for (int off = 32; off; off >>= 1) {
    sq += __shfl_down(sq, off);
    sm += __shfl_down(sm, off);
  }
  __shared__ float rs[4], rm[4];
  int wid = tid >> 6, lane = tid & 63;
  if (lane == 0) { rs[wid] = sq; rm[wid] = sm; }
  __syncthreads();
  if (tid == 0) {
    float tsq = rs[0] + rs[1] + rs[2] + rs[3];
    float tsm = rm[0] + rm[1] + rm[2] + rm[3];
    if (isP) { p2[row] = tsq; psum[row] = tsm; }
    else     { f2[row] = tsq; }
  }
}

// ---------------- mask counts: intra_count, inter_count ----------------
__global__ void mask_count_kernel(const float* __restrict__ counts,
                                  const float* __restrict__ psum, float* accum) {
  int tid = threadIdx.x;
  int ni = 0, nj = 0, nd = 0;
  for (int i = tid; i < NC; i += 256) {
    int mi = counts[i] > 0.f;
    int mj = psum[i] != 0.f;
    ni += mi; nj += mj; nd += (mi & mj);
  }
  #pragma unroll
  for (int off = 32; off; off >>= 1) {
    ni += __shfl_down(ni, off);
    nj += __shfl_down(nj, off);
    nd += __shfl_down(nd, off);
  }
  __shared__ int r0[4], r1[4], r2[4];
  int wid = tid >> 6, lane = tid & 63;
  if (lane == 0) { r0[wid] = ni; r1[wid] = nj; r2[wid] = nd; }
  __syncthreads();
  if (tid == 0) {
    float fni = (float)(r0[0] + r0[1] + r0[2] + r0[3]);
    float fnj = (float)(r1[0] + r1[1] + r1[2] + r1[3]);
    float fnd = (float)(r2[0] + r2[1] + r2[2] + r2[3]);
    accum[2] = fnd;                 // intra_count
    accum[3] = fni * fnj - fnd;     // inter_count
  }
}

// ---------------- fused GEMM + loss reduction ----------------
#define GLDS(gsrc, ldst)                                                     \
  __builtin_amdgcn_global_load_lds(                                          \
      (__attribute__((address_space(1))) void*)(void*)(gsrc),                \
      (__attribute__((address_space(3))) void*)(void*)(ldst), 16, 0, 0)

__global__ __launch_bounds__(256)
void gemm_loss_kernel(const unsigned short* __restrict__ Fb,
                      const unsigned short* __restrict__ Pb,
                      const float* __restrict__ f2, const float* __restrict__ p2,
                      const float* __restrict__ counts, const float* __restrict__ psum,
                      float* accum) {
  __shared__ __attribute__((aligned(16))) unsigned short sA[128 * 64];
  __shared__ __attribute__((aligned(16))) unsigned short sB[128 * 64];
  const int bid = blockIdx.x;
  const int bi = bid >> 5, bj = bid & 31;       // 32x32 tiles of 128x128
  const int tid = threadIdx.x;
  const int lane = tid & 63, wid = tid >> 6;
  const int wrow = wid >> 1, wcol = wid & 1;    // 2x2 wave grid, 64x64 each
  const int lo = lane & 15, hi = lane >> 4;

  // Staging: linear LDS dest (global_load_lds constraint), pre-swizzled
  // global source so that swizzled ds_read reconstructs the logical tile.
  size_t aoff[4], boff[4];
  int loff[4];
  #pragma unroll
  for (int it = 0; it < 4; ++it) {
    int idx = it * 256 + tid;                  // 16B chunk index (0..1023)
    int srow = idx >> 3;                       // row 0..127
    int scol = ((idx & 7) ^ (srow & 7)) * 8;   // swizzled k-start (elements)
    loff[it] = idx * 8;                        // ushort offset in LDS
    aoff[it] = (size_t)(bi * 128 + srow) * ND + scol;
    boff[it] = (size_t)(bj * 128 + srow) * ND + scol;
  }

  f32x4 zero = {0.f, 0.f, 0.f, 0.f};
  f32x4 acc[4][4];
  #pragma unroll
  for (int m = 0; m < 4; ++m)
    #pragma unroll
    for (int n = 0; n < 4; ++n) acc[m][n] = zero;

  for (int kt = 0; kt < ND / 64; ++kt) {
    __syncthreads();                            // prior tile reads done
    #pragma unroll
    for (int it = 0; it < 4; ++it) {
      GLDS(Fb + aoff[it] + kt * 64, &sA[loff[it]]);
      GLDS(Pb + boff[it] + kt * 64, &sB[loff[it]]);
    }
    __syncthreads();                            // staging complete (vmcnt drain)
    #pragma unroll
    for (int ks = 0; ks < 2; ++ks) {
      bf16x8 av[4], bv[4];
      #pragma unroll
      for (int m = 0; m < 4; ++m) {
        int row = wrow * 64 + m * 16 + lo;
        int kb = ks * 64 + hi * 16;             // byte offset in 128B row
        int off = row * 64 + ((kb ^ ((row & 7) << 4)) >> 1);
        av[m] = *reinterpret_cast<const bf16x8*>(&sA[off]);
      }
      #pragma unroll
      for (int n = 0; n < 4; ++n) {
        int row = wcol * 64 + n * 16 + lo;
        int kb = ks * 64 + hi * 16;
        int off = row * 64 + ((kb ^ ((row & 7) << 4)) >> 1);
        bv[n] = *reinterpret_cast<const bf16x8*>(&sB[off]);
      }
      #pragma unroll
      for (int m = 0; m < 4; ++m)
        #pragma unroll
        for (int n = 0; n < 4; ++n)
          acc[m][n] = __builtin_amdgcn_mfma_f32_16x16x32_bf16(av[m], bv[n], acc[m][n], 0, 0, 0);
    }
  }

  // Epilogue: per-element msd -> intra (diag) / inter (off-diag) partials.
  // C/D layout (m89-verified): col = lane&15, row = (lane>>4)*4 + reg.
  float intra_l = 0.f, inter_l = 0.f;
  const int gi0 = bi * 128 + wrow * 64 + hi * 4;
  const int gj0 = bj * 128 + wcol * 64 + lo;
  float f2i[16];
  int mi[16];
  #pragma unroll
  for (int m = 0; m < 4; ++m)
    #pragma unroll
    for (int r = 0; r < 4; ++r) {
      int gi = gi0 + m * 16 + r;
      f2i[m * 4 + r] = f2[gi];
      mi[m * 4 + r] = counts[gi] > 0.f;
    }
  #pragma unroll
  for (int n = 0; n < 4; ++n) {
    int gj = gj0 + n * 16;
    float p2j = p2[gj];
    bool mj = psum[gj] != 0.f;
    if (mj) {
      #pragma unroll
      for (int m = 0; m < 4; ++m) {
        #pragma unroll
        for (int r = 0; r < 4; ++r) {
          if (!mi[m * 4 + r]) continue;
          int gi = gi0 + m * 16 + r;
          float cij = acc[m][n][r];
          float msd = fmaxf(f2i[m * 4 + r] + p2j - 2.f * cij, 0.f) * (1.f / 1024.f);
          if (gi == gj) {
            intra_l += msd;                       // diagonal: intra
          } else if (msd < 1.0f) {                // inter term nonzero only if sqrt(msd)<1
            float s = sqrtf(fmaxf(msd, 1e-12f));
            float e = 1.f - s;
            float e2 = e * e;
            inter_l += e2 * e2;                   // (e/M)^2 * max(e,0)^2, M=1
          }
        }
      }
    }
  }
  #pragma unroll
  for (int off = 32; off; off >>= 1) {
    intra_l += __shfl_down(intra_l, off);
    inter_l += __shfl_down(inter_l, off);
  }
  __shared__ float redI[4], redE[4];
  if (lane == 0) { redI[wid] = intra_l; redE[wid] = inter_l; }
  __syncthreads();
  if (tid == 0) {
    atomicAdd(&accum[0], redI[0] + redI[1] + redI[2] + redI[3]);
    atomicAdd(&accum[1], redE[0] + redE[1] + redE[2] + redE[3]);
  }
}

// ---------------- finalize ----------------
__global__ void finalize_kernel(const float* __restrict__ accum, float* __restrict__ out) {
  if (threadIdx.x == 0) {
    out[0] = accum[0] / (accum[2] + EPSF);
    out[1] = accum[1] / (accum[3] + EPSF);
  }
}

extern "C" void kernel_launch(void* const* d_in, const int* in_sizes, int n_in,
                              void* d_out, int out_size, void* d_ws, size_t ws_size,
                              hipStream_t stream) {
  const float* F = (const float*)d_in[0];
  const float* P = (const float*)d_in[1];
  const int* ann = (const int*)d_in[2];
  int n_ann = in_sizes[2] / 5;

  char* ws = (char*)d_ws;
  unsigned short* Fb = (unsigned short*)ws;                          // 8 MB
  unsigned short* Pb = (unsigned short*)(ws + (size_t)NC * ND * 2);  // 8 MB
  float* f2    = (float*)(ws + (size_t)NC * ND * 4);
  float* p2    = f2 + NC;
  float* psum  = p2 + NC;
  float* counts = psum + NC;
  float* accum  = counts + NC;   // [0]=intra_sum [1]=inter_sum [2]=intra_cnt [3]=inter_cnt
  float* out = (float*)d_out;

  zero_kernel<<<(NC + 8 + 255) / 256, 256, 0, stream>>>(counts, NC + 8);
  count_kernel<<<(n_ann + 255) / 256, 256, 0, stream>>>(ann, counts, n_ann);
  convert_kernel<<<2 * NC, 256, 0, stream>>>(F, P, Fb, Pb, f2, p2, psum);
  mask_count_kernel<<<1, 256, 0, stream>>>(counts, psum, accum);
  gemm_loss_kernel<<<(NC / 128) * (NC / 128), 256, 0, stream>>>(Fb, Pb, f2, p2, counts, psum, accum);
  finalize_kernel<<<1, 64, 0, stream>>>(accum, out);
}

// Round 2
// 64.509 us; speedup vs baseline: 1.3808x; 1.3808x over previous
//
#include <hip/hip_runtime.h>
#include <hip/hip_bf16.h>

typedef float f32x4 __attribute__((ext_vector_type(4)));
typedef __bf16 bf16x8 __attribute__((ext_vector_type(8)));

#define NC 4096
#define ND 1024
#define EPSF 1e-10f
#define NT 16  // K-tiles of BK=64

__device__ __forceinline__ unsigned short f2bf(float f) {
  unsigned int u = __float_as_uint(f);
  return (unsigned short)((u + 0x7fffu + ((u >> 16) & 1u)) >> 16);
}

// ---------------- zero accumulators + scatter-count (fused, 1 block) ----------------
__global__ void init_count_kernel(const int* __restrict__ ann, float* counts, int n) {
  int tid = threadIdx.x;
  for (int i = tid; i < NC + 8; i += 256) counts[i] = 0.f;
  __syncthreads();
  for (int t = tid; t < n; t += 256) {
    int idx = ann[t * 5 + 4];
    if (idx >= 0 && idx < NC) atomicAdd(&counts[idx], 1.0f);
  }
}

// ---------------- fp32 -> bf16 convert + row norms/sums ----------------
__global__ void convert_kernel(const float* __restrict__ F, const float* __restrict__ P,
                               unsigned short* __restrict__ Fb, unsigned short* __restrict__ Pb,
                               float* __restrict__ f2, float* __restrict__ p2,
                               float* __restrict__ psum) {
  int bid = blockIdx.x;
  bool isP = bid >= NC;
  int row = isP ? bid - NC : bid;
  const float* src = (isP ? P : F) + (size_t)row * ND;
  unsigned short* dst = (isP ? Pb : Fb) + (size_t)row * ND;
  int tid = threadIdx.x;
  float4 v = *reinterpret_cast<const float4*>(src + tid * 4);
  ushort4 o;
  o.x = f2bf(v.x); o.y = f2bf(v.y); o.z = f2bf(v.z); o.w = f2bf(v.w);
  *reinterpret_cast<ushort4*>(dst + tid * 4) = o;
  float sq = v.x * v.x + v.y * v.y + v.z * v.z + v.w * v.w;
  float sm = v.x + v.y + v.z + v.w;
  #pragma unroll
  for (int off = 32; off; off >>= 1) {
    sq += __shfl_down(sq, off);
    sm += __shfl_down(sm, off);
  }
  __shared__ float rs[4], rm[4];
  int wid = tid >> 6, lane = tid & 63;
  if (lane == 0) { rs[wid] = sq; rm[wid] = sm; }
  __syncthreads();
  if (tid == 0) {
    float tsq = rs[0] + rs[1] + rs[2] + rs[3];
    float tsm = rm[0] + rm[1] + rm[2] + rm[3];
    if (isP) { p2[row] = tsq; psum[row] = tsm; }
    else     { f2[row] = tsq; }
  }
}

// ---------------- fused 256x256 8-phase GEMM + loss reduction ----------------
#define GLDS(gsrc, ldst)                                                     \
  __builtin_amdgcn_global_load_lds(                                          \
      (__attribute__((address_space(1))) void*)(void*)(gsrc),                \
      (__attribute__((address_space(3))) void*)(void*)(ldst), 16, 0, 0)

#define FENCE() asm volatile("" ::: "memory")
#define BAR()  do { FENCE(); __builtin_amdgcn_s_barrier(); FENCE(); } while (0)
#define VMCNT4() asm volatile("s_waitcnt vmcnt(4)" ::: "memory")

// Stage half-tile h (0=A0,1=A1,2=B0,3=B1) of K-tile kt into dbuf d.
// Linear LDS dest (global_load_lds constraint), inverse-swizzled global
// source; ds_read applies the matching XOR (rule 21: both-sides swizzle).
#define STAGE(d, h, kt)                                                       \
  do {                                                                        \
    const unsigned short* _m = ((h) < 2) ? Fb : Pb;                           \
    size_t _rb = (((h) < 2) ? arow : brow) + (size_t)(((h) & 1) * 128) * ND;  \
    _Pragma("unroll")                                                         \
    for (int _c = 0; _c < 2; ++_c)                                            \
      GLDS(_m + _rb + (size_t)srow[_c] * ND + (size_t)(kt) * 64 + scol[_c],   \
           &lds[d][h][ldso[_c]]);                                             \
  } while (0)

#define LDA(DB, QM)                                                           \
  do {                                                                        \
    const char* _b = (const char*)&lds[DB][wr][0];                            \
    _Pragma("unroll")                                                         \
    for (int _mm = 0; _mm < 4; ++_mm)                                         \
      _Pragma("unroll")                                                       \
      for (int _kk = 0; _kk < 2; ++_kk) {                                     \
        int _r = (QM) * 64 + _mm * 16 + lo;                                   \
        int _kb = _kk * 64 + hi * 16;                                         \
        av[_mm * 2 + _kk] =                                                   \
            *(const bf16x8*)(_b + _r * 128 + (_kb ^ ((_r & 7) << 4)));        \
      }                                                                       \
  } while (0)

#define LDB(DB, QN, BV)                                                       \
  do {                                                                        \
    const char* _b = (const char*)&lds[DB][2 + (wc >> 1)][0];                 \
    _Pragma("unroll")                                                         \
    for (int _nn = 0; _nn < 2; ++_nn)                                         \
      _Pragma("unroll")                                                       \
      for (int _kk = 0; _kk < 2; ++_kk) {                                     \
        int _r = (wc & 1) * 64 + (QN) * 32 + _nn * 16 + lo;                   \
        int _kb = _kk * 64 + hi * 16;                                         \
        BV[_nn * 2 + _kk] =                                                   \
            *(const bf16x8*)(_b + _r * 128 + (_kb ^ ((_r & 7) << 4)));        \
      }                                                                       \
  } while (0)

#define MMA(QM, QN, BV)                                                       \
  do {                                                                        \
    __builtin_amdgcn_s_setprio(1);                                            \
    _Pragma("unroll")                                                         \
    for (int _mm = 0; _mm < 4; ++_mm)                                         \
      _Pragma("unroll")                                                       \
      for (int _nn = 0; _nn < 2; ++_nn)                                       \
        _Pragma("unroll")                                                     \
        for (int _kk = 0; _kk < 2; ++_kk)                                     \
          acc[(QM) * 4 + _mm][(QN) * 2 + _nn] =                               \
              __builtin_amdgcn_mfma_f32_16x16x32_bf16(                        \
                  av[_mm * 2 + _kk], BV[_nn * 2 + _kk],                       \
                  acc[(QM) * 4 + _mm][(QN) * 2 + _nn], 0, 0, 0);              \
    __builtin_amdgcn_s_setprio(0);                                            \
  } while (0)

__global__ __launch_bounds__(512, 2)
void gemm_loss_kernel(const unsigned short* __restrict__ Fb,
                      const unsigned short* __restrict__ Pb,
                      const float* __restrict__ f2, const float* __restrict__ p2,
                      const float* __restrict__ counts, const float* __restrict__ psum,
                      float* accum) {
  // [dbuf][half: A0,A1,B0,B1][128x64 bf16 = 16 KiB]  => 128 KiB total
  __shared__ __attribute__((aligned(16))) unsigned short lds[2][4][8192];
  __shared__ float redI[8], redE[8];

  // XCD-bijective swizzle: 256 wgs, 8 XCDs, 32 contiguous tiles (2 bi-rows) each
  const int wg = (blockIdx.x & 7) * 32 + (blockIdx.x >> 3);
  const int bi = wg >> 4, bj = wg & 15;

  const int tid = threadIdx.x;
  const int lane = tid & 63, wid = tid >> 6;
  const int wr = wid >> 2, wc = wid & 3;  // 2 (M) x 4 (N) wave grid; 128x64 per wave
  const int lo = lane & 15, hi = lane >> 4;

  // staging chunk geometry: 1024 chunks of 16B per half-tile, 2 per thread
  int srow[2], scol[2], ldso[2];
  #pragma unroll
  for (int c = 0; c < 2; ++c) {
    int idx = c * 512 + tid;
    srow[c] = idx >> 3;
    scol[c] = ((idx & 7) ^ (srow[c] & 7)) * 8;
    ldso[c] = idx * 8;
  }
  const size_t arow = (size_t)(bi * 256) * ND;
  const size_t brow = (size_t)(bj * 256) * ND;

  bf16x8 av[8], bv0[4], bv1[4];
  f32x4 acc[8][4];
  f32x4 zero = {0.f, 0.f, 0.f, 0.f};
  #pragma unroll
  for (int m = 0; m < 8; ++m)
    #pragma unroll
    for (int n = 0; n < 4; ++n) acc[m][n] = zero;

  // Prologue: K-tile 0 fully into dbuf0; B-halves of K-tile 1 into dbuf1
  // (A-halves of odd K-tiles are staged at phases 1,2 of each iteration).
  STAGE(0, 0, 0); STAGE(0, 1, 0); STAGE(0, 2, 0); STAGE(0, 3, 0);
  STAGE(1, 2, 1); STAGE(1, 3, 1);
  VMCNT4();  // dbuf0 landed; dbuf1's 4 B-loads may remain in flight
  BAR();

  // 8 iterations, 2 K-tiles each: even K-tile in dbuf0 (phases 1-4),
  // odd in dbuf1 (phases 5-8). Quadrants: P1=(qm0,qn0) P2=(qm0,qn1)
  // P3=(qm1,qn0) P4=(qm1,qn1). A-halves consumed by P3, B by P2 =>
  // stage-into-self schedule below is race-free behind barriers.
  #pragma unroll 1
  for (int it = 0; it < NT / 2; ++it) {
    const int k1 = 2 * it + 1, kn0 = 2 * it + 2, kn1 = 2 * it + 3;
    // P1
    LDA(0, 0); LDB(0, 0, bv0);
    STAGE(1, 0, k1);                       // A0 of k1 (read last at prev P7)
    BAR(); MMA(0, 0, bv0); BAR();
    // P2
    LDB(0, 1, bv1);
    STAGE(1, 1, k1);                       // A1 of k1
    BAR(); MMA(0, 1, bv1); BAR();
    // P3
    LDA(0, 1);
    if (kn0 < NT) STAGE(0, 2, kn0);        // B0 of k0+2 (B consumed by P2)
    BAR(); MMA(1, 0, bv0); BAR();
    // P4
    if (kn0 < NT) STAGE(0, 3, kn0);        // B1 of k0+2
    VMCNT4();                              // dbuf1 (k1) fully landed
    BAR(); MMA(1, 1, bv1); BAR();
    // P5
    LDA(1, 0); LDB(1, 0, bv0);
    if (kn0 < NT) STAGE(0, 0, kn0);        // A0 of k0+2 (A consumed by P3)
    BAR(); MMA(0, 0, bv0); BAR();
    // P6
    LDB(1, 1, bv1);
    if (kn0 < NT) STAGE(0, 1, kn0);        // A1 of k0+2
    BAR(); MMA(0, 1, bv1); BAR();
    // P7
    LDA(1, 1);
    if (kn1 < NT) STAGE(1, 2, kn1);        // B0 of k1+2 (dbuf1 B consumed by P6)
    BAR(); MMA(1, 0, bv0); BAR();
    // P8
    if (kn1 < NT) STAGE(1, 3, kn1);        // B1 of k1+2
    VMCNT4();                              // dbuf0 (k0+2) fully landed
    BAR(); MMA(1, 1, bv1); BAR();
  }

  // Epilogue: per-element msd -> intra (diag) / inter (off-diag) partials.
  // C/D layout (m89-verified): col = lane&15, row = (lane>>4)*4 + reg.
  float intra_l = 0.f, inter_l = 0.f;
  const int gi0 = bi * 256 + wr * 128 + hi * 4;
  const int gj0 = bj * 256 + wc * 64 + lo;
  float f2i[32];
  int mi[32];
  #pragma unroll
  for (int m = 0; m < 8; ++m)
    #pragma unroll
    for (int r = 0; r < 4; ++r) {
      int gi = gi0 + m * 16 + r;
      f2i[m * 4 + r] = f2[gi];
      mi[m * 4 + r] = counts[gi] > 0.f;
    }
  #pragma unroll
  for (int n = 0; n < 4; ++n) {
    int gj = gj0 + n * 16;
    float p2j = p2[gj];
    bool mj = psum[gj] != 0.f;
    if (mj) {
      #pragma unroll
      for (int m = 0; m < 8; ++m) {
        #pragma unroll
        for (int r = 0; r < 4; ++r) {
          if (!mi[m * 4 + r]) continue;
          int gi = gi0 + m * 16 + r;
          float cij = acc[m][n][r];
          float msd = fmaxf(f2i[m * 4 + r] + p2j - 2.f * cij, 0.f) * (1.f / 1024.f);
          if (gi == gj) {
            intra_l += msd;                 // diagonal: intra
          } else if (msd < 1.0f) {          // inter term nonzero only if sqrt(msd)<1
            float s = sqrtf(fmaxf(msd, 1e-12f));
            float e = 1.f - s;
            float e2 = e * e;
            inter_l += e2 * e2;             // (e/M)^2 * max(e,0)^2, M=1
          }
        }
      }
    }
  }
  #pragma unroll
  for (int off = 32; off; off >>= 1) {
    intra_l += __shfl_down(intra_l, off);
    inter_l += __shfl_down(inter_l, off);
  }
  if (lane == 0) { redI[wid] = intra_l; redE[wid] = inter_l; }
  __syncthreads();
  if (tid == 0) {
    float si = 0.f, se = 0.f;
    #pragma unroll
    for (int w = 0; w < 8; ++w) { si += redI[w]; se += redE[w]; }
    atomicAdd(&accum[0], si);
    atomicAdd(&accum[1], se);
  }
}

// ---------------- mask counts + finalize (fused) ----------------
__global__ void finalize_kernel(const float* __restrict__ counts,
                                const float* __restrict__ psum,
                                const float* __restrict__ accum,
                                float* __restrict__ out) {
  int tid = threadIdx.x;
  int ni = 0, nj = 0, nd = 0;
  for (int i = tid; i < NC; i += 256) {
    int mi = counts[i] > 0.f;
    int mj = psum[i] != 0.f;
    ni += mi; nj += mj; nd += (mi & mj);
  }
  #pragma unroll
  for (int off = 32; off; off >>= 1) {
    ni += __shfl_down(ni, off);
    nj += __shfl_down(nj, off);
    nd += __shfl_down(nd, off);
  }
  __shared__ int r0[4], r1[4], r2[4];
  int wid = tid >> 6, lane = tid & 63;
  if (lane == 0) { r0[wid] = ni; r1[wid] = nj; r2[wid] = nd; }
  __syncthreads();
  if (tid == 0) {
    float fni = (float)(r0[0] + r0[1] + r0[2] + r0[3]);
    float fnj = (float)(r1[0] + r1[1] + r1[2] + r1[3]);
    float fnd = (float)(r2[0] + r2[1] + r2[2] + r2[3]);
    out[0] = accum[0] / (fnd + EPSF);
    out[1] = accum[1] / (fni * fnj - fnd + EPSF);
  }
}

extern "C" void kernel_launch(void* const* d_in, const int* in_sizes, int n_in,
                              void* d_out, int out_size, void* d_ws, size_t ws_size,
                              hipStream_t stream) {
  const float* F = (const float*)d_in[0];
  const float* P = (const float*)d_in[1];
  const int* ann = (const int*)d_in[2];
  int n_ann = in_sizes[2] / 5;

  char* ws = (char*)d_ws;
  unsigned short* Fb = (unsigned short*)ws;                          // 8 MB
  unsigned short* Pb = (unsigned short*)(ws + (size_t)NC * ND * 2);  // 8 MB
  float* f2     = (float*)(ws + (size_t)NC * ND * 4);
  float* p2     = f2 + NC;
  float* psum   = p2 + NC;
  float* counts = psum + NC;
  float* accum  = counts + NC;  // [0]=intra_sum [1]=inter_sum

  float* out = (float*)d_out;

  init_count_kernel<<<1, 256, 0, stream>>>(ann, counts, n_ann);
  convert_kernel<<<2 * NC, 256, 0, stream>>>(F, P, Fb, Pb, f2, p2, psum);
  gemm_loss_kernel<<<(NC / 256) * (NC / 256), 512, 0, stream>>>(Fb, Pb, f2, p2, counts, psum, accum);
  finalize_kernel<<<1, 256, 0, stream>>>(counts, psum, accum, out);
}